// Round 3
// baseline (500.182 us; speedup 1.0000x reference)
//
#include <hip/hip_runtime.h>
#include <math.h>

#define B_  8192
#define E_  8
#define D_  3072
#define H_  256
#define C_  100
#define DH_ (D_*H_)
#define HC_ (H_*C_)
#define KS_ 8            // K splits in gemm1
#define KSEG_ (D_/KS_)   // 384
#define RKS_ 8           // K splits in router
#define RSEG_ (D_/RKS_)  // 384
#define NTMAX_ 136       // max 64-row tiles over all experts (128+8 slack)

typedef __attribute__((ext_vector_type(4))) float  f32x4;
typedef __attribute__((ext_vector_type(8))) __bf16 bf16x8;
typedef __attribute__((ext_vector_type(8))) unsigned short ush8;
typedef __attribute__((ext_vector_type(4))) unsigned short ush4;

__device__ inline unsigned short bf16_rne(float f) {
    unsigned u = __builtin_bit_cast(unsigned, f);
    unsigned r = (u + 0x7FFFu + ((u >> 16) & 1u)) >> 16;
    return (unsigned short)r;
}
__device__ inline float bf16_f(unsigned short h) {
    unsigned u = ((unsigned)h) << 16;
    return __builtin_bit_cast(float, u);
}

// ---------------------------------------------------------------------------
// Fused small blends: b1 (E*H), b2 (E*C) fp32 blends + router weights fp64.
// One launch replaces blend4_k x2 + blendrw_k.
// ---------------------------------------------------------------------------
#define MISC_B1_ (E_*H_/4)            // 512 float4
#define MISC_B2_ (E_*C_/4)            // 200 float4
#define MISC_TOT_ (MISC_B1_ + MISC_B2_ + D_)
__global__ __launch_bounds__(256) void blend_misc_k(
        const float* __restrict__ b1, const float* __restrict__ b2,
        const float* __restrict__ rw, float* __restrict__ B1b,
        float* __restrict__ B2b, double* __restrict__ wsd,
        const float* __restrict__ coeffs) {
    int gid = blockIdx.x * 256 + threadIdx.x;
    float c0 = coeffs[0], c1 = coeffs[1];
    if (gid < MISC_B1_) {
        const float4* p = (const float4*)b1;
        int e = gid / (H_ / 4), r = gid - e * (H_ / 4);
        float4 a = p[(e * 2 + 0) * (H_ / 4) + r];
        float4 bq = p[(e * 2 + 1) * (H_ / 4) + r];
        float4 o;
        o.x = c0 * a.x + c1 * bq.x;
        o.y = c0 * a.y + c1 * bq.y;
        o.z = c0 * a.z + c1 * bq.z;
        o.w = c0 * a.w + c1 * bq.w;
        ((float4*)B1b)[gid] = o;
    } else if (gid < MISC_B1_ + MISC_B2_) {
        int g2 = gid - MISC_B1_;
        const float4* p = (const float4*)b2;
        int e = g2 / (C_ / 4), r = g2 - e * (C_ / 4);
        float4 a = p[(e * 2 + 0) * (C_ / 4) + r];
        float4 bq = p[(e * 2 + 1) * (C_ / 4) + r];
        float4 o;
        o.x = c0 * a.x + c1 * bq.x;
        o.y = c0 * a.y + c1 * bq.y;
        o.z = c0 * a.z + c1 * bq.z;
        o.w = c0 * a.w + c1 * bq.w;
        ((float4*)B2b)[g2] = o;
    } else {
        int d = gid - (MISC_B1_ + MISC_B2_);
        if (d < D_) {
            double c0d = (double)c0, c1d = (double)c1;
            #pragma unroll
            for (int ee = 0; ee < 8; ee++)
                wsd[(size_t)d * 8 + ee] = c0d * (double)rw[(size_t)d * 8 + ee]
                                        + c1d * (double)rw[(size_t)(D_ + d) * 8 + ee];
        }
    }
}

// ---------------------------------------------------------------------------
// W1 blend + bf16 hi/lo split + transpose to [e][h][d], via LDS so BOTH
// global reads (over h) and writes (over d) are 256B-contiguous.
// Tile: 64 h x 128 d. Grid (D/128, H/64, E).
// ---------------------------------------------------------------------------
#define TP_ 136   // LDS pitch in ushorts (272 B, 16B-aligned rows)
__global__ __launch_bounds__(256) void blendw1t_k(
        const float* __restrict__ w1, unsigned short* __restrict__ Whi,
        unsigned short* __restrict__ Wlo, const float* __restrict__ coeffs) {
    __shared__ unsigned short thi[64 * TP_];
    __shared__ unsigned short tlo[64 * TP_];
    float c0 = coeffs[0], c1 = coeffs[1];
    int t = threadIdx.x;
    int e = blockIdx.z, h0 = blockIdx.y * 64, d0 = blockIdx.x * 128;
    int h = t & 63, dl = t >> 6;
    const float* pa = w1 + ((size_t)(e * 2 + 0) * D_ + d0) * H_ + h0 + h;
    const float* pb = w1 + ((size_t)(e * 2 + 1) * D_ + d0) * H_ + h0 + h;
    for (int it = 0; it < 32; it++) {
        int d = it * 4 + dl;
        float v = c0 * pa[(size_t)d * H_] + c1 * pb[(size_t)d * H_];
        unsigned short hi = bf16_rne(v);
        thi[h * TP_ + d] = hi;
        tlo[h * TP_ + d] = bf16_rne(v - bf16_f(hi));
    }
    __syncthreads();
    #pragma unroll
    for (int it = 0; it < 4; it++) {
        int i = t + it * 256;
        int hh = i >> 4, d8 = (i & 15) * 8;
        size_t g = (size_t)(e * H_ + h0 + hh) * D_ + d0 + d8;
        *(ush8*)(Whi + g) = *(const ush8*)&thi[hh * TP_ + d8];
        *(ush8*)(Wlo + g) = *(const ush8*)&tlo[hh * TP_ + d8];
    }
}

// ---------------------------------------------------------------------------
// W2 blend + bf16 hi/lo split + transpose to [e][c][k] (stride C_, no pad;
// gemm2's padded-column reads overrun harmlessly into adjacent ws arrays).
// ---------------------------------------------------------------------------
__global__ __launch_bounds__(256) void blendw2t_k(
        const float* __restrict__ w2, unsigned short* __restrict__ W2thi,
        unsigned short* __restrict__ W2tlo, const float* __restrict__ coeffs) {
    float c0 = coeffs[0], c1 = coeffs[1];
    int c = blockIdx.x, e = blockIdx.y, k = threadIdx.x;
    float v = c0 * w2[((size_t)(e * 2 + 0) * H_ + k) * C_ + c]
            + c1 * w2[((size_t)(e * 2 + 1) * H_ + k) * C_ + c];
    unsigned short hi = bf16_rne(v);
    W2thi[(size_t)(e * C_ + c) * H_ + k] = hi;
    W2tlo[(size_t)(e * C_ + c) * H_ + k] = bf16_rne(v - bf16_f(hi));
}

// ---------------------------------------------------------------------------
// Router fp64 GEMV, VALU. 1 wave/block, lane owns a row, 8 fp64 acc in regs.
// RKS_=8 -> 1024 blocks = 4 waves/CU for latency hiding.
// ---------------------------------------------------------------------------
__global__ __launch_bounds__(64) void router_v2_k(
        const float* __restrict__ x, const double* __restrict__ wsd,
        double* __restrict__ lpart) {
    __shared__ float  xs[64][33];
    __shared__ double wls[32][8];
    int lane = threadIdx.x;
    int row0 = blockIdx.x * 64;
    int kbase = blockIdx.y * RSEG_;

    double acc[8] = {0, 0, 0, 0, 0, 0, 0, 0};

    for (int kb = 0; kb < RSEG_; kb += 32) {
        #pragma unroll
        for (int it = 0; it < 8; it++) {
            int i = lane + it * 64;
            int r = i >> 3, c4 = i & 7;
            *(float4*)&xs[r][c4 * 4] =
                *(const float4*)(x + (size_t)(row0 + r) * D_ + kbase + kb + c4 * 4);
        }
        #pragma unroll
        for (int it = 0; it < 4; it++) {
            int i = lane + it * 64;
            int k = i >> 3, ee = i & 7;
            wls[k][ee] = wsd[(size_t)(kbase + kb + k) * 8 + ee];
        }
        __syncthreads();
        #pragma unroll
        for (int kk = 0; kk < 32; kk++) {
            double xv = (double)xs[lane][kk];
            double2 w01 = *(const double2*)&wls[kk][0];
            double2 w23 = *(const double2*)&wls[kk][2];
            double2 w45 = *(const double2*)&wls[kk][4];
            double2 w67 = *(const double2*)&wls[kk][6];
            acc[0] = fma(xv, w01.x, acc[0]);
            acc[1] = fma(xv, w01.y, acc[1]);
            acc[2] = fma(xv, w23.x, acc[2]);
            acc[3] = fma(xv, w23.y, acc[3]);
            acc[4] = fma(xv, w45.x, acc[4]);
            acc[5] = fma(xv, w45.y, acc[5]);
            acc[6] = fma(xv, w67.x, acc[6]);
            acc[7] = fma(xv, w67.y, acc[7]);
        }
        __syncthreads();
    }
    size_t base = ((size_t)blockIdx.y * B_ + row0 + lane) * 8;
    #pragma unroll
    for (int ee = 0; ee < 8; ee++) lpart[base + ee] = acc[ee];
}

// ---------------------------------------------------------------------------
// Combine partials + bias, fp64 argmax (strict > = np first-max), counts.
// ---------------------------------------------------------------------------
__global__ __launch_bounds__(256) void argmax_k(
        const double* __restrict__ lpart, const float* __restrict__ rb,
        const float* __restrict__ coeffs, int* __restrict__ idx,
        int* __restrict__ cnt) {
    __shared__ int scnt[8];
    int t = threadIdx.x;
    if (t < 8) scnt[t] = 0;
    __syncthreads();
    int b = blockIdx.x * 256 + t;
    double c0 = (double)coeffs[0], c1 = (double)coeffs[1];
    double best = -1e300;
    int bi = 0;
    #pragma unroll
    for (int e = 0; e < 8; e++) {
        double l = c0 * (double)rb[e] + c1 * (double)rb[8 + e];
        #pragma unroll
        for (int s2 = 0; s2 < RKS_; s2++)
            l += lpart[((size_t)s2 * B_ + b) * 8 + e];
        if (l > best) { best = l; bi = e; }
    }
    idx[b] = bi;
    atomicAdd(&scnt[bi], 1);
    __syncthreads();
    if (t < 8 && scnt[t] > 0) atomicAdd(&cnt[t], scnt[t]);
}

// ---------------------------------------------------------------------------
// Prefix offsets + compact tile map: tmap[i] = (e<<16) | tile0
// ---------------------------------------------------------------------------
__global__ void offsets_k(const int* __restrict__ cnt, int* __restrict__ off,
                          int* __restrict__ cursor, int* __restrict__ tmap,
                          int* __restrict__ ntl) {
    if (threadIdx.x == 0) {
        int s = 0;
        for (int e = 0; e < E_; e++) { off[e] = s; cursor[e] = s; s += cnt[e]; }
        int nt = 0;
        for (int e = 0; e < E_; e++)
            for (int t0 = 0; t0 < cnt[e]; t0 += 64)
                tmap[nt++] = (e << 16) | t0;
        ntl[0] = nt;
    }
}

// order entries pack expert + row: (e<<16) | b
__global__ void scatter_k(const int* __restrict__ idx, int* __restrict__ cursor,
                          int* __restrict__ order) {
    int b = blockIdx.x * blockDim.x + threadIdx.x;
    if (b < B_) {
        int e = idx[b];
        int pos = atomicAdd(&cursor[e], 1);
        order[pos] = (e << 16) | b;
    }
}

// ---------------------------------------------------------------------------
// GEMM1 via bf16x2-split MFMA (hh, lh, hl, ll), fp32 AGPR acc.
// Grid (KS, NTMAX): blockIdx.x = K-slice s fastest -> slice s pins to XCD s
// (weights L2-resident per XCD; partial-slice writes are XCD-local).
// Pipeline (T14): all staging addresses hoisted; per chunk:
//   ds_write current (from prefetch regs) -> barrier -> issue next chunk's
//   global loads -> ds_read + MFMA (setprio) -> barrier.
// Next chunk's HBM/L2 latency hides under current chunk's 64 MFMAs.
// MODE=1: plain stores into dst + s*B_*H_ (per-slice partials, no atomics).
// MODE=0: legacy atomicAdd into dst (= hws), small-workspace fallback.
// ---------------------------------------------------------------------------
template<int MODE>
__global__ __launch_bounds__(256, 3) void gemm1_t(
        const float* __restrict__ x, const unsigned short* __restrict__ Whi,
        const unsigned short* __restrict__ Wlo, const int* __restrict__ order,
        const int* __restrict__ cnt, const int* __restrict__ off,
        const int* __restrict__ tmap, const int* __restrict__ ntl,
        float* __restrict__ dst) {
    int tid = blockIdx.y;
    if (tid >= ntl[0]) return;
    int tm = tmap[tid];
    int e = tm >> 16, tile0 = tm & 0xFFFF;
    int ce = cnt[e];
    int s = blockIdx.x;

    __shared__ int rows[64];
    __shared__ unsigned short xs_hi[64 * 40];
    __shared__ unsigned short xs_lo[64 * 40];
    __shared__ unsigned short ws_hi[256 * 40];
    __shared__ unsigned short ws_lo[256 * 40];

    int t = threadIdx.x;
    if (t < 64) {
        int i = tile0 + t;
        rows[t] = (i < ce) ? (order[off[e] + i] & 0xFFFF) : -1;
    }
    __syncthreads();
    int xrow0 = rows[0];

    int lane = t & 63, w = t >> 6;
    int lr = lane & 15, quad = lane >> 4;
    int kbase = s * KSEG_;

    // ---- hoisted staging addresses (invariant over K-chunks) ----
    // x staging: thread covers (rr0, sg) and (rr1, sg)
    int sg = t & 7;
    int rr0 = t >> 3, rr1 = (t + 256) >> 3;
    int rowa = rows[rr0]; if (rowa < 0) rowa = xrow0;
    int rowb = rows[rr1]; if (rowb < 0) rowb = xrow0;
    const float* xp0 = x + (size_t)rowa * D_ + kbase + sg * 4;
    const float* xp1 = x + (size_t)rowb * D_ + kbase + sg * 4;
    int xo0 = rr0 * 40 + sg * 4, xo1 = rr1 * 40 + sg * 4;
    // w staging: 4 assignments per thread
    size_t wgo[4];
    int wdo[4];
    #pragma unroll
    for (int it = 0; it < 4; it++) {
        int i = t + it * 256;
        int col = i >> 2, ch = i & 3;
        wgo[it] = (size_t)(e * H_ + col) * D_ + kbase + ch * 8;
        wdo[it] = col * 40 + ch * 8;
    }

    f32x4 acc[4][4];
    #pragma unroll
    for (int mt = 0; mt < 4; mt++)
        #pragma unroll
        for (int nt = 0; nt < 4; nt++)
            acc[mt][nt] = (f32x4){0.f, 0.f, 0.f, 0.f};

    // ---- prologue: prefetch chunk 0 into registers ----
    float4 px0 = *(const float4*)xp0;
    float4 px1 = *(const float4*)xp1;
    ush8 pwh[4], pwl[4];
    #pragma unroll
    for (int it = 0; it < 4; it++) {
        pwh[it] = *(const ush8*)(Whi + wgo[it]);
        pwl[it] = *(const ush8*)(Wlo + wgo[it]);
    }

    for (int kb = 0; kb < KSEG_; kb += 32) {
        // ---- phase A: convert + ds_write current chunk from regs ----
        {
            float vv[4] = {px0.x, px0.y, px0.z, px0.w};
            unsigned short h4[4], l4[4];
            #pragma unroll
            for (int j = 0; j < 4; j++) {
                unsigned short hi = bf16_rne(vv[j]);
                h4[j] = hi;
                l4[j] = bf16_rne(vv[j] - bf16_f(hi));
            }
            *(ush4*)&xs_hi[xo0] = *(const ush4*)h4;
            *(ush4*)&xs_lo[xo0] = *(const ush4*)l4;
        }
        {
            float vv[4] = {px1.x, px1.y, px1.z, px1.w};
            unsigned short h4[4], l4[4];
            #pragma unroll
            for (int j = 0; j < 4; j++) {
                unsigned short hi = bf16_rne(vv[j]);
                h4[j] = hi;
                l4[j] = bf16_rne(vv[j] - bf16_f(hi));
            }
            *(ush4*)&xs_hi[xo1] = *(const ush4*)h4;
            *(ush4*)&xs_lo[xo1] = *(const ush4*)l4;
        }
        #pragma unroll
        for (int it = 0; it < 4; it++) {
            *(ush8*)&ws_hi[wdo[it]] = pwh[it];
            *(ush8*)&ws_lo[wdo[it]] = pwl[it];
        }
        __syncthreads();

        // ---- issue next chunk's global loads (land under MFMA) ----
        if (kb + 32 < KSEG_) {
            px0 = *(const float4*)(xp0 + kb + 32);
            px1 = *(const float4*)(xp1 + kb + 32);
            #pragma unroll
            for (int it = 0; it < 4; it++) {
                pwh[it] = *(const ush8*)(Whi + wgo[it] + kb + 32);
                pwl[it] = *(const ush8*)(Wlo + wgo[it] + kb + 32);
            }
        }

        // ---- phase B: fragments + MFMA ----
        bf16x8 ah[4], al[4], bh[4], bl[4];
        #pragma unroll
        for (int mt = 0; mt < 4; mt++) {
            ah[mt] = __builtin_bit_cast(bf16x8, *(const ush8*)&xs_hi[(mt * 16 + lr) * 40 + quad * 8]);
            al[mt] = __builtin_bit_cast(bf16x8, *(const ush8*)&xs_lo[(mt * 16 + lr) * 40 + quad * 8]);
        }
        #pragma unroll
        for (int nt = 0; nt < 4; nt++) {
            int col = w * 64 + nt * 16 + lr;
            bh[nt] = __builtin_bit_cast(bf16x8, *(const ush8*)&ws_hi[col * 40 + quad * 8]);
            bl[nt] = __builtin_bit_cast(bf16x8, *(const ush8*)&ws_lo[col * 40 + quad * 8]);
        }
        __builtin_amdgcn_s_setprio(1);
        #pragma unroll
        for (int mt = 0; mt < 4; mt++)
            #pragma unroll
            for (int nt = 0; nt < 4; nt++) {
                acc[mt][nt] = __builtin_amdgcn_mfma_f32_16x16x32_bf16(ah[mt], bh[nt], acc[mt][nt], 0, 0, 0);
                acc[mt][nt] = __builtin_amdgcn_mfma_f32_16x16x32_bf16(al[mt], bh[nt], acc[mt][nt], 0, 0, 0);
                acc[mt][nt] = __builtin_amdgcn_mfma_f32_16x16x32_bf16(ah[mt], bl[nt], acc[mt][nt], 0, 0, 0);
                acc[mt][nt] = __builtin_amdgcn_mfma_f32_16x16x32_bf16(al[mt], bl[nt], acc[mt][nt], 0, 0, 0);
            }
        __builtin_amdgcn_s_setprio(0);
        __syncthreads();
    }

    size_t p0 = (size_t)off[e] + tile0;
    if (MODE == 1) {
        // per-slice partial, plain stores (XCD-local L2 writeback)
        float* dp = dst + ((size_t)s * B_ + p0) * H_;
        #pragma unroll
        for (int mt = 0; mt < 4; mt++) {
            int rl = mt * 16 + quad * 4;
            #pragma unroll
            for (int nt = 0; nt < 4; nt++) {
                int col = w * 64 + nt * 16 + lr;
                #pragma unroll
                for (int rg = 0; rg < 4; rg++) {
                    if (tile0 + rl + rg < ce)
                        dp[(size_t)(rl + rg) * H_ + col] = acc[mt][nt][rg];
                }
            }
        }
    } else {
        #pragma unroll
        for (int mt = 0; mt < 4; mt++) {
            int rl = mt * 16 + quad * 4;
            #pragma unroll
            for (int nt = 0; nt < 4; nt++) {
                int col = w * 64 + nt * 16 + lr;
                #pragma unroll
                for (int rg = 0; rg < 4; rg++) {
                    if (tile0 + rl + rg < ce)
                        atomicAdd(&dst[(p0 + rl + rg) * H_ + col], acc[mt][nt][rg]);
                }
            }
        }
    }
}

// ---------------------------------------------------------------------------
// Sum the KS_ partial slices + bias + exact GELU -> slice 0 (= hws), in place.
// ---------------------------------------------------------------------------
__global__ __launch_bounds__(256) void reduce_gelu_k(
        float* __restrict__ hpart, const float* __restrict__ B1b,
        const int* __restrict__ order) {
    int gid = blockIdx.x * 256 + threadIdx.x;
    int p = gid >> 6, c4 = (gid & 63) * 4;
    int e = order[p] >> 16;
    size_t o = (size_t)p * H_ + c4;
    float4 a = *(const float4*)(hpart + o);
    #pragma unroll
    for (int s2 = 1; s2 < KS_; s2++) {
        float4 b = *(const float4*)(hpart + (size_t)s2 * B_ * H_ + o);
        a.x += b.x; a.y += b.y; a.z += b.z; a.w += b.w;
    }
    const float4 bb = *(const float4*)(B1b + e * H_ + c4);
    float pre[4] = {a.x + bb.x, a.y + bb.y, a.z + bb.z, a.w + bb.w};
    float4 og;
    og.x = 0.5f * pre[0] * (1.0f + erff(pre[0] * 0.70710678118654752440f));
    og.y = 0.5f * pre[1] * (1.0f + erff(pre[1] * 0.70710678118654752440f));
    og.z = 0.5f * pre[2] * (1.0f + erff(pre[2] * 0.70710678118654752440f));
    og.w = 0.5f * pre[3] * (1.0f + erff(pre[3] * 0.70710678118654752440f));
    *(float4*)(hpart + o) = og;
}

// ---------------------------------------------------------------------------
// bias + exact GELU, in place on hws (fp32) — legacy fallback path
// ---------------------------------------------------------------------------
__global__ __launch_bounds__(256) void bias_gelu_k(
        float* __restrict__ hws, const float* __restrict__ B1b,
        const int* __restrict__ order) {
    int gid = blockIdx.x * 256 + threadIdx.x;
    int p = gid >> 6, c4 = (gid & 63) * 4;
    int e = order[p] >> 16;
    float4 v = *(const float4*)(hws + (size_t)p * H_ + c4);
    const float4 bb = *(const float4*)(B1b + e * H_ + c4);
    float pre[4] = {v.x + bb.x, v.y + bb.y, v.z + bb.z, v.w + bb.w};
    float4 o;
    o.x = 0.5f * pre[0] * (1.0f + erff(pre[0] * 0.70710678118654752440f));
    o.y = 0.5f * pre[1] * (1.0f + erff(pre[1] * 0.70710678118654752440f));
    o.z = 0.5f * pre[2] * (1.0f + erff(pre[2] * 0.70710678118654752440f));
    o.w = 0.5f * pre[3] * (1.0f + erff(pre[3] * 0.70710678118654752440f));
    *(float4*)(hws + (size_t)p * H_ + c4) = o;
}

// ---------------------------------------------------------------------------
// GEMM2 via bf16x2-split MFMA; A split in registers from fp32 hws,
// B from W2t planes (L2-resident). Compact grid (NTMAX).
// ---------------------------------------------------------------------------
__global__ __launch_bounds__(256) void gemm2_k(
        const float* __restrict__ hws,
        const unsigned short* __restrict__ W2thi, const unsigned short* __restrict__ W2tlo,
        const float* __restrict__ B2b, const int* __restrict__ order,
        const int* __restrict__ cnt, const int* __restrict__ off,
        const int* __restrict__ tmap, const int* __restrict__ ntl,
        float* __restrict__ out) {
    int tid = blockIdx.x;
    if (tid >= ntl[0]) return;
    int tm = tmap[tid];
    int e = tm >> 16, tile0 = tm & 0xFFFF;
    int ce = cnt[e];

    __shared__ int rows[64];
    int t = threadIdx.x;
    if (t < 64) {
        int i = tile0 + t;
        rows[t] = (i < ce) ? (order[off[e] + i] & 0xFFFF) : -1;
    }
    __syncthreads();

    int lane = t & 63, w = t >> 6;
    int m = lane & 15, q = lane >> 4;
    int lr = w * 16 + m;
    int p = off[e] + tile0 + ((tile0 + lr < ce) ? lr : 0);

    f32x4 acc[7];
    #pragma unroll
    for (int nt = 0; nt < 7; nt++) acc[nt] = (f32x4){0.f, 0.f, 0.f, 0.f};

    const unsigned short* w2h = W2thi + (size_t)e * C_ * H_;
    const unsigned short* w2l = W2tlo + (size_t)e * C_ * H_;

    #pragma unroll
    for (int s = 0; s < 8; s++) {
        float4 v0 = *(const float4*)(hws + (size_t)p * H_ + s * 32 + q * 8);
        float4 v1 = *(const float4*)(hws + (size_t)p * H_ + s * 32 + q * 8 + 4);
        float f[8] = {v0.x, v0.y, v0.z, v0.w, v1.x, v1.y, v1.z, v1.w};
        unsigned short hh[8], lo[8];
        #pragma unroll
        for (int j = 0; j < 8; j++) {
            unsigned short hi = bf16_rne(f[j]);
            hh[j] = hi;
            lo[j] = bf16_rne(f[j] - bf16_f(hi));
        }
        bf16x8 ah = __builtin_bit_cast(bf16x8, *(const ush8*)hh);
        bf16x8 al = __builtin_bit_cast(bf16x8, *(const ush8*)lo);
        #pragma unroll
        for (int nt = 0; nt < 7; nt++) {
            // cols >= C_ read past the unpadded plane into adjacent ws arrays;
            // results land in discarded lanes only (MFMA cols independent).
            size_t bo = (size_t)(nt * 16 + m) * H_ + s * 32 + q * 8;
            bf16x8 bh = __builtin_bit_cast(bf16x8, *(const ush8*)(w2h + bo));
            bf16x8 bl = __builtin_bit_cast(bf16x8, *(const ush8*)(w2l + bo));
            acc[nt] = __builtin_amdgcn_mfma_f32_16x16x32_bf16(ah, bh, acc[nt], 0, 0, 0);
            acc[nt] = __builtin_amdgcn_mfma_f32_16x16x32_bf16(al, bh, acc[nt], 0, 0, 0);
            acc[nt] = __builtin_amdgcn_mfma_f32_16x16x32_bf16(ah, bl, acc[nt], 0, 0, 0);
            acc[nt] = __builtin_amdgcn_mfma_f32_16x16x32_bf16(al, bl, acc[nt], 0, 0, 0);
        }
    }

    #pragma unroll
    for (int nt = 0; nt < 7; nt++) {
        int c = nt * 16 + m;
        if (c >= C_) continue;
        float bias = B2b[e * C_ + c];
        #pragma unroll
        for (int i = 0; i < 4; i++) {
            int lrow = w * 16 + q * 4 + i;
            if (tile0 + lrow < ce)
                out[(size_t)rows[lrow] * C_ + c] = acc[nt][i] + bias;
        }
    }
}

// ---------------------------------------------------------------------------
extern "C" void kernel_launch(void* const* d_in, const int* in_sizes, int n_in,
                              void* d_out, int out_size, void* d_ws, size_t ws_size,
                              hipStream_t stream) {
    const float* x        = (const float*)d_in[0];
    const float* coeffs   = (const float*)d_in[1];
    const float* router_w = (const float*)d_in[2];
    const float* router_b = (const float*)d_in[3];
    const float* w1       = (const float*)d_in[4];
    const float* b1       = (const float*)d_in[5];
    const float* w2       = (const float*)d_in[6];
    const float* b2       = (const float*)d_in[7];
    float* out = (float*)d_out;

    // workspace layout: fixed 26MB prefix, then hws / hpart region
    unsigned short* Whi   = (unsigned short*)d_ws;        // E*H*D ush
    unsigned short* Wlo   = Whi + (size_t)E_ * DH_;
    unsigned short* W2thi = Wlo + (size_t)E_ * DH_;       // E*C*H ush (no pad)
    unsigned short* W2tlo = W2thi + (size_t)E_ * C_ * H_;
    float* B1b  = (float*)(W2tlo + (size_t)E_ * C_ * H_); // E*H
    float* B2b  = B1b + (size_t)E_ * H_;                  // E*C
    int* order  = (int*)(B2b + E_ * C_);                  // B (packed e<<16|b)
    int* cnt    = order + B_;                             // 8
    int* off    = cnt + E_;                               // 8
    int* cursor = off + E_;                               // 8
    int* tmap   = cursor + E_;                            // NTMAX
    int* ntl    = tmap + NTMAX_;                          // 4 (pad to 16B)
    float* hws  = (float*)(ntl + 4);                      // B*H f32 (slice 0)
    // transient aliases inside hws/hpart region (dead before gemm1):
    double* lpart = (double*)hws;                                  // RKS*B*8 f64 (4 MB)
    double* wsd   = (double*)((char*)hws + (size_t)RKS_ * B_ * 8 * 8);  // D*8 f64 @ +4MB
    int*    idx   = (int*)((char*)hws + (5u << 20));               // B ints @ +5MB

    size_t prefix_bytes = (size_t)((char*)hws - (char*)d_ws);
    // partial-store path needs KS_ fp32 slices of B_*H_
    int use_part = (ws_size >= prefix_bytes + (size_t)KS_ * B_ * H_ * sizeof(float) + 256) ? 1 : 0;

    hipMemsetAsync(cnt, 0, 3 * E_ * sizeof(int), stream);

    blendw1t_k<<<dim3(D_ / 128, H_ / 64, E_), 256, 0, stream>>>(w1, Whi, Wlo, coeffs);
    blendw2t_k<<<dim3(C_, E_), 256, 0, stream>>>(w2, W2thi, W2tlo, coeffs);
    blend_misc_k<<<dim3((MISC_TOT_ + 255) / 256), 256, 0, stream>>>(
        b1, b2, router_w, B1b, B2b, wsd, coeffs);

    router_v2_k<<<dim3(B_ / 64, RKS_), 64, 0, stream>>>(x, wsd, lpart);
    argmax_k<<<dim3(B_ / 256), 256, 0, stream>>>(lpart, router_b, coeffs, idx, cnt);
    offsets_k<<<1, 64, 0, stream>>>(cnt, off, cursor, tmap, ntl);
    scatter_k<<<dim3(B_ / 256), 256, 0, stream>>>(idx, cursor, order);

    if (use_part) {
        // no memset needed: every (s,p,h) partial is written by exactly one block
        gemm1_t<1><<<dim3(KS_, NTMAX_), 256, 0, stream>>>(x, Whi, Wlo, order, cnt,
                                                          off, tmap, ntl, hws);
        reduce_gelu_k<<<dim3(B_ * H_ / 4 / 256), 256, 0, stream>>>(hws, B1b, order);
    } else {
        // legacy: zero hws (lpart/wsd/idx aliases dead), atomic partial sums
        hipMemsetAsync(hws, 0, (size_t)B_ * H_ * sizeof(float), stream);
        gemm1_t<0><<<dim3(KS_, NTMAX_), 256, 0, stream>>>(x, Whi, Wlo, order, cnt,
                                                          off, tmap, ntl, hws);
        bias_gelu_k<<<dim3(B_ * H_ / 4 / 256), 256, 0, stream>>>(hws, B1b, order);
    }
    gemm2_k<<<dim3(NTMAX_), 256, 0, stream>>>(hws, W2thi, W2tlo, B2b, order,
                                              cnt, off, tmap, ntl, out);
}

// Round 5
// 363.130 us; speedup vs baseline: 1.3774x; 1.3774x over previous
//
#include <hip/hip_runtime.h>
#include <math.h>

#define B_  8192
#define E_  8
#define D_  3072
#define H_  256
#define C_  100
#define DH_ (D_*H_)
#define HC_ (H_*C_)
#define KS_ 8            // K splits in gemm1
#define KSEG_ (D_/KS_)   // 384
#define NTMAX_ 136       // max 64-row tiles over all experts (128+8 slack)

typedef __attribute__((ext_vector_type(4))) float  f32x4;
typedef __attribute__((ext_vector_type(8))) __bf16 bf16x8;
typedef __attribute__((ext_vector_type(8))) unsigned short ush8;
typedef __attribute__((ext_vector_type(4))) unsigned short ush4;

__device__ inline unsigned short bf16_rne(float f) {
    unsigned u = __builtin_bit_cast(unsigned, f);
    unsigned r = (u + 0x7FFFu + ((u >> 16) & 1u)) >> 16;
    return (unsigned short)r;
}
__device__ inline float bf16_f(unsigned short h) {
    unsigned u = ((unsigned)h) << 16;
    return __builtin_bit_cast(float, u);
}

// ---------------------------------------------------------------------------
// Fused small blends: b1 (E*H), b2 (E*C) fp32 blends + router weights fp64.
// ---------------------------------------------------------------------------
#define MISC_B1_ (E_*H_/4)            // 512 float4
#define MISC_B2_ (E_*C_/4)            // 200 float4
#define MISC_TOT_ (MISC_B1_ + MISC_B2_ + D_)
__global__ __launch_bounds__(256) void blend_misc_k(
        const float* __restrict__ b1, const float* __restrict__ b2,
        const float* __restrict__ rw, float* __restrict__ B1b,
        float* __restrict__ B2b, double* __restrict__ wsd,
        const float* __restrict__ coeffs) {
    int gid = blockIdx.x * 256 + threadIdx.x;
    float c0 = coeffs[0], c1 = coeffs[1];
    if (gid < MISC_B1_) {
        const float4* p = (const float4*)b1;
        int e = gid / (H_ / 4), r = gid - e * (H_ / 4);
        float4 a = p[(e * 2 + 0) * (H_ / 4) + r];
        float4 bq = p[(e * 2 + 1) * (H_ / 4) + r];
        float4 o;
        o.x = c0 * a.x + c1 * bq.x;
        o.y = c0 * a.y + c1 * bq.y;
        o.z = c0 * a.z + c1 * bq.z;
        o.w = c0 * a.w + c1 * bq.w;
        ((float4*)B1b)[gid] = o;
    } else if (gid < MISC_B1_ + MISC_B2_) {
        int g2 = gid - MISC_B1_;
        const float4* p = (const float4*)b2;
        int e = g2 / (C_ / 4), r = g2 - e * (C_ / 4);
        float4 a = p[(e * 2 + 0) * (C_ / 4) + r];
        float4 bq = p[(e * 2 + 1) * (C_ / 4) + r];
        float4 o;
        o.x = c0 * a.x + c1 * bq.x;
        o.y = c0 * a.y + c1 * bq.y;
        o.z = c0 * a.z + c1 * bq.z;
        o.w = c0 * a.w + c1 * bq.w;
        ((float4*)B2b)[g2] = o;
    } else {
        int d = gid - (MISC_B1_ + MISC_B2_);
        if (d < D_) {
            double c0d = (double)c0, c1d = (double)c1;
            #pragma unroll
            for (int ee = 0; ee < 8; ee++)
                wsd[(size_t)d * 8 + ee] = c0d * (double)rw[(size_t)d * 8 + ee]
                                        + c1d * (double)rw[(size_t)(D_ + d) * 8 + ee];
        }
    }
}

// ---------------------------------------------------------------------------
// W1 blend + bf16 hi/lo split + transpose to [e][h][d], via LDS so BOTH
// global reads (over h) and writes (over d) are 256B-contiguous.
// Tile: 64 h x 128 d. Grid (D/128, H/64, E).
// ---------------------------------------------------------------------------
#define TP_ 136   // LDS pitch in ushorts (272 B, 16B-aligned rows)
__global__ __launch_bounds__(256) void blendw1t_k(
        const float* __restrict__ w1, unsigned short* __restrict__ Whi,
        unsigned short* __restrict__ Wlo, const float* __restrict__ coeffs) {
    __shared__ unsigned short thi[64 * TP_];
    __shared__ unsigned short tlo[64 * TP_];
    float c0 = coeffs[0], c1 = coeffs[1];
    int t = threadIdx.x;
    int e = blockIdx.z, h0 = blockIdx.y * 64, d0 = blockIdx.x * 128;
    int h = t & 63, dl = t >> 6;
    const float* pa = w1 + ((size_t)(e * 2 + 0) * D_ + d0) * H_ + h0 + h;
    const float* pb = w1 + ((size_t)(e * 2 + 1) * D_ + d0) * H_ + h0 + h;
    for (int it = 0; it < 32; it++) {
        int d = it * 4 + dl;
        float v = c0 * pa[(size_t)d * H_] + c1 * pb[(size_t)d * H_];
        unsigned short hi = bf16_rne(v);
        thi[h * TP_ + d] = hi;
        tlo[h * TP_ + d] = bf16_rne(v - bf16_f(hi));
    }
    __syncthreads();
    #pragma unroll
    for (int it = 0; it < 4; it++) {
        int i = t + it * 256;
        int hh = i >> 4, d8 = (i & 15) * 8;
        size_t g = (size_t)(e * H_ + h0 + hh) * D_ + d0 + d8;
        *(ush8*)(Whi + g) = *(const ush8*)&thi[hh * TP_ + d8];
        *(ush8*)(Wlo + g) = *(const ush8*)&tlo[hh * TP_ + d8];
    }
}

// ---------------------------------------------------------------------------
// W2 blend + bf16 hi/lo split + transpose to [e][c][k] (stride C_, no pad;
// gemm2's padded-column reads overrun harmlessly into adjacent ws arrays).
// ---------------------------------------------------------------------------
__global__ __launch_bounds__(256) void blendw2t_k(
        const float* __restrict__ w2, unsigned short* __restrict__ W2thi,
        unsigned short* __restrict__ W2tlo, const float* __restrict__ coeffs) {
    float c0 = coeffs[0], c1 = coeffs[1];
    int c = blockIdx.x, e = blockIdx.y, k = threadIdx.x;
    float v = c0 * w2[((size_t)(e * 2 + 0) * H_ + k) * C_ + c]
            + c1 * w2[((size_t)(e * 2 + 1) * H_ + k) * C_ + c];
    unsigned short hi = bf16_rne(v);
    W2thi[(size_t)(e * C_ + c) * H_ + k] = hi;
    W2tlo[(size_t)(e * C_ + c) * H_ + k] = bf16_rne(v - bf16_f(hi));
}

// ---------------------------------------------------------------------------
// Router fp64 GEMV, VALU. 1 wave/block, lane owns a row, 8 fp64 acc in regs.
// RKS=16 -> 2048 blocks = 8 waves/CU; RKS=8 fallback (small workspace).
// ---------------------------------------------------------------------------
template<int RKS>
__global__ __launch_bounds__(64) void router_v2_t(
        const float* __restrict__ x, const double* __restrict__ wsd,
        double* __restrict__ lpart) {
    const int RSEG = D_ / RKS;
    __shared__ float  xs[64][33];
    __shared__ double wls[32][8];
    int lane = threadIdx.x;
    int row0 = blockIdx.x * 64;
    int kbase = blockIdx.y * RSEG;

    double acc[8] = {0, 0, 0, 0, 0, 0, 0, 0};

    for (int kb = 0; kb < RSEG; kb += 32) {
        #pragma unroll
        for (int it = 0; it < 8; it++) {
            int i = lane + it * 64;
            int r = i >> 3, c4 = i & 7;
            *(float4*)&xs[r][c4 * 4] =
                *(const float4*)(x + (size_t)(row0 + r) * D_ + kbase + kb + c4 * 4);
        }
        #pragma unroll
        for (int it = 0; it < 4; it++) {
            int i = lane + it * 64;
            int k = i >> 3, ee = i & 7;
            wls[k][ee] = wsd[(size_t)(kbase + kb + k) * 8 + ee];
        }
        __syncthreads();
        #pragma unroll
        for (int kk = 0; kk < 32; kk++) {
            double xv = (double)xs[lane][kk];
            double2 w01 = *(const double2*)&wls[kk][0];
            double2 w23 = *(const double2*)&wls[kk][2];
            double2 w45 = *(const double2*)&wls[kk][4];
            double2 w67 = *(const double2*)&wls[kk][6];
            acc[0] = fma(xv, w01.x, acc[0]);
            acc[1] = fma(xv, w01.y, acc[1]);
            acc[2] = fma(xv, w23.x, acc[2]);
            acc[3] = fma(xv, w23.y, acc[3]);
            acc[4] = fma(xv, w45.x, acc[4]);
            acc[5] = fma(xv, w45.y, acc[5]);
            acc[6] = fma(xv, w67.x, acc[6]);
            acc[7] = fma(xv, w67.y, acc[7]);
        }
        __syncthreads();
    }
    size_t base = ((size_t)blockIdx.y * B_ + row0 + lane) * 8;
    #pragma unroll
    for (int ee = 0; ee < 8; ee++) lpart[base + ee] = acc[ee];
}

// ---------------------------------------------------------------------------
// Combine partials + bias, fp64 argmax (strict > = np first-max), counts.
// ---------------------------------------------------------------------------
template<int RKS>
__global__ __launch_bounds__(256) void argmax_t(
        const double* __restrict__ lpart, const float* __restrict__ rb,
        const float* __restrict__ coeffs, int* __restrict__ idx,
        int* __restrict__ cnt) {
    __shared__ int scnt[8];
    int t = threadIdx.x;
    if (t < 8) scnt[t] = 0;
    __syncthreads();
    int b = blockIdx.x * 256 + t;
    double c0 = (double)coeffs[0], c1 = (double)coeffs[1];
    double best = -1e300;
    int bi = 0;
    #pragma unroll
    for (int e = 0; e < 8; e++) {
        double l = c0 * (double)rb[e] + c1 * (double)rb[8 + e];
        #pragma unroll
        for (int s2 = 0; s2 < RKS; s2++)
            l += lpart[((size_t)s2 * B_ + b) * 8 + e];
        if (l > best) { best = l; bi = e; }
    }
    idx[b] = bi;
    atomicAdd(&scnt[bi], 1);
    __syncthreads();
    if (t < 8 && scnt[t] > 0) atomicAdd(&cnt[t], scnt[t]);
}

// ---------------------------------------------------------------------------
// Prefix offsets + compact tile map: tmap[i] = (e<<16) | tile0
// ---------------------------------------------------------------------------
__global__ void offsets_k(const int* __restrict__ cnt, int* __restrict__ off,
                          int* __restrict__ cursor, int* __restrict__ tmap,
                          int* __restrict__ ntl) {
    if (threadIdx.x == 0) {
        int s = 0;
        for (int e = 0; e < E_; e++) { off[e] = s; cursor[e] = s; s += cnt[e]; }
        int nt = 0;
        for (int e = 0; e < E_; e++)
            for (int t0 = 0; t0 < cnt[e]; t0 += 64)
                tmap[nt++] = (e << 16) | t0;
        ntl[0] = nt;
    }
}

// order entries pack expert + row: (e<<16) | b
__global__ void scatter_k(const int* __restrict__ idx, int* __restrict__ cursor,
                          int* __restrict__ order) {
    int b = blockIdx.x * blockDim.x + threadIdx.x;
    if (b < B_) {
        int e = idx[b];
        int pos = atomicAdd(&cursor[e], 1);
        order[pos] = (e << 16) | b;
    }
}

// ---------------------------------------------------------------------------
// GEMM1 via bf16x2-split MFMA (hh, lh, hl, ll), fp32 AGPR acc.
// Grid (KS, NTMAX): blockIdx.x = K-slice s fastest -> slice s pins to XCD s
// (weights L2-resident per XCD; partial-slice writes are XCD-local).
// MODE=1: plain stores into dst + s*B_*H_ (per-slice partials, no atomics).
// MODE=0: legacy atomicAdd into dst (= hws), small-workspace fallback.
// NOTE: round-3's register-prefetch variant spilled (launch_bounds cap) and
// regressed 3x; this is the proven round-2 body.
// ---------------------------------------------------------------------------
template<int MODE>
__global__ __launch_bounds__(256, 3) void gemm1_t(
        const float* __restrict__ x, const unsigned short* __restrict__ Whi,
        const unsigned short* __restrict__ Wlo, const int* __restrict__ order,
        const int* __restrict__ cnt, const int* __restrict__ off,
        const int* __restrict__ tmap, const int* __restrict__ ntl,
        float* __restrict__ dst) {
    int tid = blockIdx.y;
    if (tid >= ntl[0]) return;
    int tm = tmap[tid];
    int e = tm >> 16, tile0 = tm & 0xFFFF;
    int ce = cnt[e];
    int s = blockIdx.x;

    __shared__ int rows[64];
    __shared__ unsigned short xs_hi[64 * 40];
    __shared__ unsigned short xs_lo[64 * 40];
    __shared__ unsigned short ws_hi[256 * 40];
    __shared__ unsigned short ws_lo[256 * 40];

    int t = threadIdx.x;
    if (t < 64) {
        int i = tile0 + t;
        rows[t] = (i < ce) ? (order[off[e] + i] & 0xFFFF) : -1;
    }
    __syncthreads();
    int xrow0 = rows[0];

    int lane = t & 63, w = t >> 6;
    int lr = lane & 15, quad = lane >> 4;
    int kbase = s * KSEG_;

    f32x4 acc[4][4];
    #pragma unroll
    for (int mt = 0; mt < 4; mt++)
        #pragma unroll
        for (int nt = 0; nt < 4; nt++)
            acc[mt][nt] = (f32x4){0.f, 0.f, 0.f, 0.f};

    for (int kb = 0; kb < KSEG_; kb += 32) {
        #pragma unroll
        for (int it = 0; it < 2; it++) {
            int i = t + it * 256;
            int rr = i >> 3, sg = i & 7;
            int row = rows[rr];
            if (row < 0) row = xrow0;
            float4 v = *(const float4*)(x + (size_t)row * D_ + kbase + kb + sg * 4);
            unsigned short h4[4], l4[4];
            float vv[4] = {v.x, v.y, v.z, v.w};
            #pragma unroll
            for (int j = 0; j < 4; j++) {
                unsigned short hi = bf16_rne(vv[j]);
                h4[j] = hi;
                l4[j] = bf16_rne(vv[j] - bf16_f(hi));
            }
            *(ush4*)&xs_hi[rr * 40 + sg * 4] = *(const ush4*)h4;
            *(ush4*)&xs_lo[rr * 40 + sg * 4] = *(const ush4*)l4;
        }
        #pragma unroll
        for (int it = 0; it < 4; it++) {
            int i = t + it * 256;
            int col = i >> 2, ch = i & 3;
            size_t g = (size_t)(e * H_ + col) * D_ + kbase + kb + ch * 8;
            *(ush8*)&ws_hi[col * 40 + ch * 8] = *(const ush8*)(Whi + g);
            *(ush8*)&ws_lo[col * 40 + ch * 8] = *(const ush8*)(Wlo + g);
        }
        __syncthreads();

        bf16x8 ah[4], al[4], bh[4], bl[4];
        #pragma unroll
        for (int mt = 0; mt < 4; mt++) {
            ah[mt] = __builtin_bit_cast(bf16x8, *(const ush8*)&xs_hi[(mt * 16 + lr) * 40 + quad * 8]);
            al[mt] = __builtin_bit_cast(bf16x8, *(const ush8*)&xs_lo[(mt * 16 + lr) * 40 + quad * 8]);
        }
        #pragma unroll
        for (int nt = 0; nt < 4; nt++) {
            int col = w * 64 + nt * 16 + lr;
            bh[nt] = __builtin_bit_cast(bf16x8, *(const ush8*)&ws_hi[col * 40 + quad * 8]);
            bl[nt] = __builtin_bit_cast(bf16x8, *(const ush8*)&ws_lo[col * 40 + quad * 8]);
        }
        #pragma unroll
        for (int mt = 0; mt < 4; mt++)
            #pragma unroll
            for (int nt = 0; nt < 4; nt++) {
                acc[mt][nt] = __builtin_amdgcn_mfma_f32_16x16x32_bf16(ah[mt], bh[nt], acc[mt][nt], 0, 0, 0);
                acc[mt][nt] = __builtin_amdgcn_mfma_f32_16x16x32_bf16(al[mt], bh[nt], acc[mt][nt], 0, 0, 0);
                acc[mt][nt] = __builtin_amdgcn_mfma_f32_16x16x32_bf16(ah[mt], bl[nt], acc[mt][nt], 0, 0, 0);
                acc[mt][nt] = __builtin_amdgcn_mfma_f32_16x16x32_bf16(al[mt], bl[nt], acc[mt][nt], 0, 0, 0);
            }
        __syncthreads();
    }

    size_t p0 = (size_t)off[e] + tile0;
    if (MODE == 1) {
        // per-slice partial, plain stores (XCD-local L2 writeback)
        float* dp = dst + ((size_t)s * B_ + p0) * H_;
        #pragma unroll
        for (int mt = 0; mt < 4; mt++) {
            int rl = mt * 16 + quad * 4;
            #pragma unroll
            for (int nt = 0; nt < 4; nt++) {
                int col = w * 64 + nt * 16 + lr;
                #pragma unroll
                for (int rg = 0; rg < 4; rg++) {
                    if (tile0 + rl + rg < ce)
                        dp[(size_t)(rl + rg) * H_ + col] = acc[mt][nt][rg];
                }
            }
        }
    } else {
        #pragma unroll
        for (int mt = 0; mt < 4; mt++) {
            int rl = mt * 16 + quad * 4;
            #pragma unroll
            for (int nt = 0; nt < 4; nt++) {
                int col = w * 64 + nt * 16 + lr;
                #pragma unroll
                for (int rg = 0; rg < 4; rg++) {
                    if (tile0 + rl + rg < ce)
                        atomicAdd(&dst[(p0 + rl + rg) * H_ + col], acc[mt][nt][rg]);
                }
            }
        }
    }
}

// ---------------------------------------------------------------------------
// Sum the KS_ partial slices + bias + exact GELU -> slice 0 (= hws), in place.
// ---------------------------------------------------------------------------
__global__ __launch_bounds__(256) void reduce_gelu_k(
        float* __restrict__ hpart, const float* __restrict__ B1b,
        const int* __restrict__ order) {
    int gid = blockIdx.x * 256 + threadIdx.x;
    int p = gid >> 6, c4 = (gid & 63) * 4;
    int e = order[p] >> 16;
    size_t o = (size_t)p * H_ + c4;
    float4 a = *(const float4*)(hpart + o);
    #pragma unroll
    for (int s2 = 1; s2 < KS_; s2++) {
        float4 b = *(const float4*)(hpart + (size_t)s2 * B_ * H_ + o);
        a.x += b.x; a.y += b.y; a.z += b.z; a.w += b.w;
    }
    const float4 bb = *(const float4*)(B1b + e * H_ + c4);
    float pre[4] = {a.x + bb.x, a.y + bb.y, a.z + bb.z, a.w + bb.w};
    float4 og;
    og.x = 0.5f * pre[0] * (1.0f + erff(pre[0] * 0.70710678118654752440f));
    og.y = 0.5f * pre[1] * (1.0f + erff(pre[1] * 0.70710678118654752440f));
    og.z = 0.5f * pre[2] * (1.0f + erff(pre[2] * 0.70710678118654752440f));
    og.w = 0.5f * pre[3] * (1.0f + erff(pre[3] * 0.70710678118654752440f));
    *(float4*)(hpart + o) = og;
}

// ---------------------------------------------------------------------------
// bias + exact GELU, in place on hws (fp32) — legacy fallback path
// ---------------------------------------------------------------------------
__global__ __launch_bounds__(256) void bias_gelu_k(
        float* __restrict__ hws, const float* __restrict__ B1b,
        const int* __restrict__ order) {
    int gid = blockIdx.x * 256 + threadIdx.x;
    int p = gid >> 6, c4 = (gid & 63) * 4;
    int e = order[p] >> 16;
    float4 v = *(const float4*)(hws + (size_t)p * H_ + c4);
    const float4 bb = *(const float4*)(B1b + e * H_ + c4);
    float pre[4] = {v.x + bb.x, v.y + bb.y, v.z + bb.z, v.w + bb.w};
    float4 o;
    o.x = 0.5f * pre[0] * (1.0f + erff(pre[0] * 0.70710678118654752440f));
    o.y = 0.5f * pre[1] * (1.0f + erff(pre[1] * 0.70710678118654752440f));
    o.z = 0.5f * pre[2] * (1.0f + erff(pre[2] * 0.70710678118654752440f));
    o.w = 0.5f * pre[3] * (1.0f + erff(pre[3] * 0.70710678118654752440f));
    *(float4*)(hws + (size_t)p * H_ + c4) = o;
}

// ---------------------------------------------------------------------------
// GEMM2 via bf16x2-split MFMA; A split in registers from fp32 hws,
// B from W2t planes (L2-resident). Compact grid (NTMAX).
// ---------------------------------------------------------------------------
__global__ __launch_bounds__(256) void gemm2_k(
        const float* __restrict__ hws,
        const unsigned short* __restrict__ W2thi, const unsigned short* __restrict__ W2tlo,
        const float* __restrict__ B2b, const int* __restrict__ order,
        const int* __restrict__ cnt, const int* __restrict__ off,
        const int* __restrict__ tmap, const int* __restrict__ ntl,
        float* __restrict__ out) {
    int tid = blockIdx.x;
    if (tid >= ntl[0]) return;
    int tm = tmap[tid];
    int e = tm >> 16, tile0 = tm & 0xFFFF;
    int ce = cnt[e];

    __shared__ int rows[64];
    int t = threadIdx.x;
    if (t < 64) {
        int i = tile0 + t;
        rows[t] = (i < ce) ? (order[off[e] + i] & 0xFFFF) : -1;
    }
    __syncthreads();

    int lane = t & 63, w = t >> 6;
    int m = lane & 15, q = lane >> 4;
    int lr = w * 16 + m;
    int p = off[e] + tile0 + ((tile0 + lr < ce) ? lr : 0);

    f32x4 acc[7];
    #pragma unroll
    for (int nt = 0; nt < 7; nt++) acc[nt] = (f32x4){0.f, 0.f, 0.f, 0.f};

    const unsigned short* w2h = W2thi + (size_t)e * C_ * H_;
    const unsigned short* w2l = W2tlo + (size_t)e * C_ * H_;

    #pragma unroll
    for (int s = 0; s < 8; s++) {
        float4 v0 = *(const float4*)(hws + (size_t)p * H_ + s * 32 + q * 8);
        float4 v1 = *(const float4*)(hws + (size_t)p * H_ + s * 32 + q * 8 + 4);
        float f[8] = {v0.x, v0.y, v0.z, v0.w, v1.x, v1.y, v1.z, v1.w};
        unsigned short hh[8], lo[8];
        #pragma unroll
        for (int j = 0; j < 8; j++) {
            unsigned short hi = bf16_rne(f[j]);
            hh[j] = hi;
            lo[j] = bf16_rne(f[j] - bf16_f(hi));
        }
        bf16x8 ah = __builtin_bit_cast(bf16x8, *(const ush8*)hh);
        bf16x8 al = __builtin_bit_cast(bf16x8, *(const ush8*)lo);
        #pragma unroll
        for (int nt = 0; nt < 7; nt++) {
            // cols >= C_ read past the unpadded plane into adjacent ws arrays;
            // results land in discarded lanes only (MFMA cols independent).
            size_t bo = (size_t)(nt * 16 + m) * H_ + s * 32 + q * 8;
            bf16x8 bh = __builtin_bit_cast(bf16x8, *(const ush8*)(w2h + bo));
            bf16x8 bl = __builtin_bit_cast(bf16x8, *(const ush8*)(w2l + bo));
            acc[nt] = __builtin_amdgcn_mfma_f32_16x16x32_bf16(ah, bh, acc[nt], 0, 0, 0);
            acc[nt] = __builtin_amdgcn_mfma_f32_16x16x32_bf16(al, bh, acc[nt], 0, 0, 0);
            acc[nt] = __builtin_amdgcn_mfma_f32_16x16x32_bf16(ah, bl, acc[nt], 0, 0, 0);
            acc[nt] = __builtin_amdgcn_mfma_f32_16x16x32_bf16(al, bl, acc[nt], 0, 0, 0);
        }
    }

    #pragma unroll
    for (int nt = 0; nt < 7; nt++) {
        int c = nt * 16 + m;
        if (c >= C_) continue;
        float bias = B2b[e * C_ + c];
        #pragma unroll
        for (int i = 0; i < 4; i++) {
            int lrow = w * 16 + q * 4 + i;
            if (tile0 + lrow < ce)
                out[(size_t)rows[lrow] * C_ + c] = acc[nt][i] + bias;
        }
    }
}

// ---------------------------------------------------------------------------
extern "C" void kernel_launch(void* const* d_in, const int* in_sizes, int n_in,
                              void* d_out, int out_size, void* d_ws, size_t ws_size,
                              hipStream_t stream) {
    const float* x        = (const float*)d_in[0];
    const float* coeffs   = (const float*)d_in[1];
    const float* router_w = (const float*)d_in[2];
    const float* router_b = (const float*)d_in[3];
    const float* w1       = (const float*)d_in[4];
    const float* b1       = (const float*)d_in[5];
    const float* w2       = (const float*)d_in[6];
    const float* b2       = (const float*)d_in[7];
    float* out = (float*)d_out;

    // workspace layout: fixed ~26MB prefix, then hws / hpart region
    unsigned short* Whi   = (unsigned short*)d_ws;        // E*H*D ush
    unsigned short* Wlo   = Whi + (size_t)E_ * DH_;
    unsigned short* W2thi = Wlo + (size_t)E_ * DH_;       // E*C*H ush (no pad)
    unsigned short* W2tlo = W2thi + (size_t)E_ * C_ * H_;
    float* B1b  = (float*)(W2tlo + (size_t)E_ * C_ * H_); // E*H
    float* B2b  = B1b + (size_t)E_ * H_;                  // E*C
    int* order  = (int*)(B2b + E_ * C_);                  // B (packed e<<16|b)
    int* cnt    = order + B_;                             // 8
    int* off    = cnt + E_;                               // 8
    int* cursor = off + E_;                               // 8
    int* tmap   = cursor + E_;                            // NTMAX
    int* ntl    = tmap + NTMAX_;                          // 4 (pad to 16B)
    float* hws  = (float*)(ntl + 4);                      // B*H f32 (slice 0)

    size_t prefix_bytes = (size_t)((char*)hws - (char*)d_ws);
    // partial-store path needs KS_ fp32 slices of B_*H_
    int use_part = (ws_size >= prefix_bytes + (size_t)KS_ * B_ * H_ * sizeof(float) + 256) ? 1 : 0;

    hipMemsetAsync(cnt, 0, 3 * E_ * sizeof(int), stream);

    blendw1t_k<<<dim3(D_ / 128, H_ / 64, E_), 256, 0, stream>>>(w1, Whi, Wlo, coeffs);
    blendw2t_k<<<dim3(C_, E_), 256, 0, stream>>>(w2, W2thi, W2tlo, coeffs);

    if (use_part) {
        // RKS=16: lpart (16*B*8 f64 = 8 MB) exactly fills hpart slice 0;
        // wsd (192 KB) + idx (32 KB) live in slice 1 — dead until gemm1
        // overwrites it (stream-ordered after scatter consumes them).
        double* lpart = (double*)hws;
        double* wsd   = (double*)(hws + (size_t)B_ * H_);           // slice 1 start
        int*    idx   = (int*)((char*)(hws + (size_t)B_ * H_) + (1u << 20));

        blend_misc_k<<<dim3((MISC_TOT_ + 255) / 256), 256, 0, stream>>>(
            b1, b2, router_w, B1b, B2b, wsd, coeffs);
        router_v2_t<16><<<dim3(B_ / 64, 16), 64, 0, stream>>>(x, wsd, lpart);
        argmax_t<16><<<dim3(B_ / 256), 256, 0, stream>>>(lpart, router_b, coeffs, idx, cnt);
        offsets_k<<<1, 64, 0, stream>>>(cnt, off, cursor, tmap, ntl);
        scatter_k<<<dim3(B_ / 256), 256, 0, stream>>>(idx, cursor, order);

        // no memset needed: every (s,p,h) partial is written by exactly one block
        gemm1_t<1><<<dim3(KS_, NTMAX_), 256, 0, stream>>>(x, Whi, Wlo, order, cnt,
                                                          off, tmap, ntl, hws);
        reduce_gelu_k<<<dim3(B_ * H_ / 4 / 256), 256, 0, stream>>>(hws, B1b, order);
    } else {
        // RKS=8 legacy layout: lpart 4MB @ slice0, wsd @ +4MB, idx @ +5MB
        double* lpart = (double*)hws;
        double* wsd   = (double*)((char*)hws + (size_t)8 * B_ * 8 * 8);
        int*    idx   = (int*)((char*)hws + (5u << 20));

        blend_misc_k<<<dim3((MISC_TOT_ + 255) / 256), 256, 0, stream>>>(
            b1, b2, router_w, B1b, B2b, wsd, coeffs);
        router_v2_t<8><<<dim3(B_ / 64, 8), 64, 0, stream>>>(x, wsd, lpart);
        argmax_t<8><<<dim3(B_ / 256), 256, 0, stream>>>(lpart, router_b, coeffs, idx, cnt);
        offsets_k<<<1, 64, 0, stream>>>(cnt, off, cursor, tmap, ntl);
        scatter_k<<<dim3(B_ / 256), 256, 0, stream>>>(idx, cursor, order);

        // zero hws (lpart alias dead), atomic partial sums
        hipMemsetAsync(hws, 0, (size_t)B_ * H_ * sizeof(float), stream);
        gemm1_t<0><<<dim3(KS_, NTMAX_), 256, 0, stream>>>(x, Whi, Wlo, order, cnt,
                                                          off, tmap, ntl, hws);
        bias_gelu_k<<<dim3(B_ * H_ / 4 / 256), 256, 0, stream>>>(hws, B1b, order);
    }
    gemm2_k<<<dim3(NTMAX_), 256, 0, stream>>>(hws, W2thi, W2tlo, B2b, order,
                                              cnt, off, tmap, ntl, out);
}